// Round 1
// baseline (468.368 us; speedup 1.0000x reference)
//
#include <hip/hip_runtime.h>
#include <math.h>

// Problem constants (match reference)
#define BB    4
#define CIN   256
#define HH    64
#define WWID  64
#define COUT  256
#define KKS   3
#define K2    9
#define PADV  1
#define HWSZ  (HH*WWID)          // 4096
#define GROUPS 32
#define CPG   (COUT/GROUPS)      // 8
#define EPSV  1e-5f
#define TP    16                 // pixels per conv block

// ---------------------------------------------------------------------------
// Kernel 1: transpose x from NCHW -> NHWC (per batch: [CIN][HW] -> [HW][CIN])
// ---------------------------------------------------------------------------
__global__ __launch_bounds__(256)
void k_transpose_x(const float* __restrict__ x, float* __restrict__ xh) {
    __shared__ float tile[32][33];
    int hw0 = blockIdx.x * 32;
    int c0  = blockIdx.y * 32;
    int b   = blockIdx.z;
    int tx = threadIdx.x;   // 0..31
    int ty = threadIdx.y;   // 0..7
    const float* xp = x  + (size_t)b * CIN * HWSZ;
    float*       op = xh + (size_t)b * HWSZ * CIN;
    #pragma unroll
    for (int i = 0; i < 32; i += 8)
        tile[ty + i][tx] = xp[(c0 + ty + i) * HWSZ + hw0 + tx];
    __syncthreads();
    #pragma unroll
    for (int i = 0; i < 32; i += 8)
        op[(hw0 + ty + i) * CIN + c0 + tx] = tile[tx][ty + i];
}

// ---------------------------------------------------------------------------
// Kernel 2: weight [Cout][Cin][K2] -> wt [K2][Cin][Cout]
// ---------------------------------------------------------------------------
__global__ __launch_bounds__(256)
void k_transpose_w(const float* __restrict__ w, float* __restrict__ wt) {
    int t = blockIdx.x * 256 + threadIdx.x;
    if (t >= K2 * CIN * COUT) return;
    int co = t % COUT;
    int ci = (t / COUT) % CIN;
    int k2 = t / (COUT * CIN);
    wt[t] = w[(co * CIN + ci) * K2 + k2];
}

// ---------------------------------------------------------------------------
// Kernel 3: per (b, pixel, k2) bilinear corner indices + weights (x mask)
// layout: [b][hw][k2][corner]  (corner = 2*iy + ix)
// ---------------------------------------------------------------------------
__global__ __launch_bounds__(256)
void k_prep(const float* __restrict__ offset, const float* __restrict__ mask,
            int* __restrict__ sidx, float* __restrict__ swgt) {
    int t = blockIdx.x * 256 + threadIdx.x;   // t = ((b*HW + hw)*K2 + k2)
    if (t >= BB * HWSZ * K2) return;
    int k2 = t % K2;
    int hw = (t / K2) % HWSZ;
    int b  = t / (K2 * HWSZ);
    int ho = hw / WWID, wo = hw % WWID;
    int ky = k2 / KKS,  kx = k2 % KKS;

    float dy = offset[((b * (2 * K2) + k2 * 2 + 0) * HWSZ) + hw];
    float dx = offset[((b * (2 * K2) + k2 * 2 + 1) * HWSZ) + hw];
    float m  = mask[(b * K2 + k2) * HWSZ + hw];

    float y = (float)(ky + ho - PADV) + dy;
    float xc = (float)(kx + wo - PADV) + dx;
    float y0f = floorf(y), x0f = floorf(xc);
    float fy = y - y0f, fx = xc - x0f;
    int y0 = (int)y0f, x0 = (int)x0f;

    int   yy[2] = { y0, y0 + 1 };
    int   xx[2] = { x0, x0 + 1 };
    float wy[2] = { 1.f - fy, fy };
    float wx[2] = { 1.f - fx, fx };

    int base = t * 4;
    #pragma unroll
    for (int i = 0; i < 2; i++) {
        #pragma unroll
        for (int j = 0; j < 2; j++) {
            int yi = yy[i], xi = xx[j];
            bool valid = (yi >= 0) && (yi < HH) && (xi >= 0) && (xi < WWID);
            int yc = min(max(yi, 0), HH - 1);
            int xcc = min(max(xi, 0), WWID - 1);
            sidx[base + i * 2 + j] = yc * WWID + xcc;
            swgt[base + i * 2 + j] = valid ? (wy[i] * wx[j] * m) : 0.f;
        }
    }
}

// ---------------------------------------------------------------------------
// Kernel 4: main deformable conv. Block = 16 pixels x 256 Cout.
// Per (k2, 64-cin chunk): sample val[16][64] into LDS, then register-tiled
// accumulate: each thread owns 4 couts (lane*4..+3) x 4 pixels (pg*4..+3).
// ---------------------------------------------------------------------------
__global__ __launch_bounds__(256)
void k_conv(const float* __restrict__ xh, const float* __restrict__ wt,
            const int* __restrict__ sidx, const float* __restrict__ swgt,
            const float* __restrict__ bias, float* __restrict__ out) {
    __shared__ int   cidx[TP * K2 * 4];
    __shared__ float cwgt[TP * K2 * 4];
    __shared__ float val[TP][64];

    int blk = blockIdx.x;
    int b   = blk / (HWSZ / TP);
    int hw0 = (blk % (HWSZ / TP)) * TP;
    int t    = threadIdx.x;
    int lane = t & 63;
    int pg   = t >> 6;          // 0..3 (wave index)

    // stage this tile's sampling coefficients (16 pix * 9 k2 * 4 corners = 576)
    int cbase = ((b * HWSZ + hw0) * K2) * 4;
    for (int i = t; i < TP * K2 * 4; i += 256) {
        cidx[i] = sidx[cbase + i];
        cwgt[i] = swgt[cbase + i];
    }

    float acc[4][4];            // [pixel q][cout j]
    #pragma unroll
    for (int q = 0; q < 4; q++)
        #pragma unroll
        for (int j = 0; j < 4; j++) acc[q][j] = 0.f;

    const float* xb = xh + (size_t)b * HWSZ * CIN;

    for (int k2 = 0; k2 < K2; k2++) {
        for (int ch = 0; ch < 4; ch++) {
            int c0 = ch * 64;
            __syncthreads();    // protects val reuse (and coef stage on iter 0)
            // ---- sampling phase: thread computes val[p][lane], p = pg*4+q
            #pragma unroll
            for (int q = 0; q < 4; q++) {
                int p  = pg * 4 + q;
                int cb = (p * K2 + k2) * 4;
                float v = 0.f;
                #pragma unroll
                for (int cor = 0; cor < 4; cor++) {
                    int   idx = cidx[cb + cor];
                    float wv  = cwgt[cb + cor];
                    v += wv * xb[idx * CIN + c0 + lane];
                }
                val[p][lane] = v;
            }
            __syncthreads();
            // ---- accumulate phase
            const float4* wrow = (const float4*)(wt + ((size_t)(k2 * CIN + c0) * COUT)) + lane;
            #pragma unroll 4
            for (int c = 0; c < 64; c++) {
                float4 w4 = wrow[c * (COUT / 4)];
                #pragma unroll
                for (int q = 0; q < 4; q++) {
                    float v = val[pg * 4 + q][c];   // wave-uniform -> LDS broadcast
                    acc[q][0] += v * w4.x;
                    acc[q][1] += v * w4.y;
                    acc[q][2] += v * w4.z;
                    acc[q][3] += v * w4.w;
                }
            }
        }
    }

    // epilogue: out[b][co][hw0 + p], co = lane*4+j; 4 contiguous pixels/store
    #pragma unroll
    for (int j = 0; j < 4; j++) {
        float bs = bias[lane * 4 + j];
        float4 o;
        o.x = acc[0][j] + bs;
        o.y = acc[1][j] + bs;
        o.z = acc[2][j] + bs;
        o.w = acc[3][j] + bs;
        *(float4*)(out + ((size_t)(b * COUT + lane * 4 + j) * HWSZ) + hw0 + pg * 4) = o;
    }
}

// ---------------------------------------------------------------------------
// Kernel 5: GroupNorm stats — one block per (b, group); mean + rstd
// ---------------------------------------------------------------------------
__global__ __launch_bounds__(256)
void k_gnstats(const float* __restrict__ out, float* __restrict__ stats) {
    int bg = blockIdx.x;                 // b*GROUPS + g
    int b = bg / GROUPS, g = bg % GROUPS;
    const float* p = out + ((size_t)(b * COUT + g * CPG)) * HWSZ;
    const int n = CPG * HWSZ;            // 32768
    float s = 0.f, ss = 0.f;
    for (int i = threadIdx.x; i < n; i += 256) {
        float v = p[i];
        s += v; ss += v * v;
    }
    #pragma unroll
    for (int o = 32; o > 0; o >>= 1) {
        s  += __shfl_down(s,  o);
        ss += __shfl_down(ss, o);
    }
    __shared__ float rs[4], rss[4];
    int w = threadIdx.x >> 6;
    if ((threadIdx.x & 63) == 0) { rs[w] = s; rss[w] = ss; }
    __syncthreads();
    if (threadIdx.x == 0) {
        s  = rs[0] + rs[1] + rs[2] + rs[3];
        ss = rss[0] + rss[1] + rss[2] + rss[3];
        float mu  = s / n;
        float var = ss / n - mu * mu;
        stats[bg * 2]     = mu;
        stats[bg * 2 + 1] = rsqrtf(var + EPSV);
    }
}

// ---------------------------------------------------------------------------
// Kernel 6: normalize + affine + ReLU, in place on d_out (float4)
// ---------------------------------------------------------------------------
__global__ __launch_bounds__(256)
void k_gnapply(float* __restrict__ out, const float* __restrict__ stats,
               const float* __restrict__ gamma, const float* __restrict__ beta) {
    int i4 = blockIdx.x * 256 + threadIdx.x;     // float4 index
    int e  = i4 * 4;
    int c  = (e / HWSZ) % COUT;
    int b  = e / (COUT * HWSZ);
    int g  = c / CPG;
    float mu   = stats[(b * GROUPS + g) * 2];
    float rstd = stats[(b * GROUPS + g) * 2 + 1];
    float ga = gamma[c] * rstd;
    float be = beta[c] - mu * ga;
    float4 v = ((float4*)out)[i4];
    v.x = fmaxf(v.x * ga + be, 0.f);
    v.y = fmaxf(v.y * ga + be, 0.f);
    v.z = fmaxf(v.z * ga + be, 0.f);
    v.w = fmaxf(v.w * ga + be, 0.f);
    ((float4*)out)[i4] = v;
}

// ---------------------------------------------------------------------------
extern "C" void kernel_launch(void* const* d_in, const int* in_sizes, int n_in,
                              void* d_out, int out_size, void* d_ws, size_t ws_size,
                              hipStream_t stream) {
    const float* x      = (const float*)d_in[0];
    const float* offset = (const float*)d_in[1];
    const float* mask   = (const float*)d_in[2];
    const float* weight = (const float*)d_in[3];
    const float* bias   = (const float*)d_in[4];
    const float* gamma  = (const float*)d_in[5];
    const float* beta   = (const float*)d_in[6];
    float* out = (float*)d_out;

    // workspace layout (all re-written every call; harness poisons ws)
    float* xh    = (float*)d_ws;                         // B*HW*CIN      = 4,194,304 f
    float* wt    = xh + (size_t)BB * HWSZ * CIN;         // K2*CIN*COUT   =   589,824 f
    int*   sidx  = (int*)(wt + (size_t)K2 * CIN * COUT); // B*HW*K2*4     =   589,824 i
    float* swgt  = (float*)(sidx + (size_t)BB * HWSZ * K2 * 4); //        =   589,824 f
    float* stats = swgt + (size_t)BB * HWSZ * K2 * 4;    // 256 f
    // total ~23.9 MB

    k_transpose_x<<<dim3(HWSZ / 32, CIN / 32, BB), dim3(32, 8), 0, stream>>>(x, xh);
    k_transpose_w<<<(K2 * CIN * COUT + 255) / 256, 256, 0, stream>>>(weight, wt);
    k_prep<<<(BB * HWSZ * K2 + 255) / 256, 256, 0, stream>>>(offset, mask, sidx, swgt);
    k_conv<<<BB * HWSZ / TP, 256, 0, stream>>>(xh, wt, sidx, swgt, bias, out);
    k_gnstats<<<BB * GROUPS, 256, 0, stream>>>(out, stats);
    k_gnapply<<<BB * COUT * HWSZ / 1024, 256, 0, stream>>>(out, stats, gamma, beta);
}

// Round 2
// 170.561 us; speedup vs baseline: 2.7460x; 2.7460x over previous
//
#include <hip/hip_runtime.h>
#include <math.h>

// Problem constants
#define BB    4
#define CIN   256
#define HH    64
#define WWID  64
#define COUT  256
#define KKS   3
#define K2    9
#define PADV  1
#define HWSZ  4096
#define GROUPS 32
#define CPG   8
#define EPSV  1e-5f
#define KTOT  2304          // K2*CIN
#define ROWB  4608          // KTOT * sizeof(bf16)
#define NTOT  16384         // BB*HWSZ
#define NCHUNK 36           // KTOT/64

typedef __attribute__((ext_vector_type(8))) short bf16x8;
typedef __attribute__((ext_vector_type(4))) float f32x4;

#define GLOAD_LDS16(g, l) \
    __builtin_amdgcn_global_load_lds((const __attribute__((address_space(1))) unsigned int*)(g), \
                                     (__attribute__((address_space(3))) unsigned int*)(l), 16, 0, 0)

__device__ __forceinline__ unsigned short f2bf(float f) {
    unsigned u = __float_as_uint(f);
    u = (u + 0x7fffu + ((u >> 16) & 1u)) >> 16;   // RNE
    return (unsigned short)u;
}

// ---------------------------------------------------------------------------
// x NCHW -> NHWC fp32 (per batch [CIN][HW] -> [HW][CIN])
// ---------------------------------------------------------------------------
__global__ __launch_bounds__(256)
void k_transpose_x(const float* __restrict__ x, float* __restrict__ xh) {
    __shared__ float tile[32][33];
    int hw0 = blockIdx.x * 32;
    int c0  = blockIdx.y * 32;
    int b   = blockIdx.z;
    int tx = threadIdx.x, ty = threadIdx.y;
    const float* xp = x  + (size_t)b * CIN * HWSZ;
    float*       op = xh + (size_t)b * HWSZ * CIN;
    #pragma unroll
    for (int i = 0; i < 32; i += 8)
        tile[ty + i][tx] = xp[(c0 + ty + i) * HWSZ + hw0 + tx];
    __syncthreads();
    #pragma unroll
    for (int i = 0; i < 32; i += 8)
        op[(hw0 + ty + i) * CIN + c0 + tx] = tile[tx][ty + i];
}

// ---------------------------------------------------------------------------
// weight [Cout][Cin][K2] fp32 -> wtb bf16 [cout][k2*256+cin], 16B-chunk
// swizzled within each 128B window by (cout&7)
// ---------------------------------------------------------------------------
__global__ __launch_bounds__(256)
void k_prep_w(const float* __restrict__ w, unsigned short* __restrict__ wtb) {
    int t = blockIdx.x * 256 + threadIdx.x;       // (co, k2, c8)
    if (t >= COUT * K2 * 32) return;
    int c8 = t & 31;
    int k2 = (t >> 5) % K2;
    int co = t / (K2 * 32);
    int cin0 = c8 * 8;
    union { unsigned short s[8]; uint4 q; } pk;
    #pragma unroll
    for (int j = 0; j < 8; j++)
        pk.s[j] = f2bf(w[(co * CIN + cin0 + j) * K2 + k2]);
    int phys = co * ROWB + k2 * 512 + (c8 >> 3) * 128 + ((c8 & 7) ^ (co & 7)) * 16;
    *(uint4*)((char*)wtb + phys) = pk.q;
}

// ---------------------------------------------------------------------------
// per (b,hw,k2): 4 bilinear corner indices + weights*mask
// ---------------------------------------------------------------------------
__global__ __launch_bounds__(256)
void k_prep(const float* __restrict__ offset, const float* __restrict__ mask,
            int* __restrict__ sidx, float* __restrict__ swgt) {
    int t = blockIdx.x * 256 + threadIdx.x;       // ((b*HW+hw)*K2 + k2)
    if (t >= BB * HWSZ * K2) return;
    int k2 = t % K2;
    int hw = (t / K2) % HWSZ;
    int b  = t / (K2 * HWSZ);
    int ho = hw / WWID, wo = hw % WWID;
    int ky = k2 / KKS,  kx = k2 % KKS;

    float dy = offset[((b * (2 * K2) + k2 * 2 + 0) * HWSZ) + hw];
    float dx = offset[((b * (2 * K2) + k2 * 2 + 1) * HWSZ) + hw];
    float m  = mask[(b * K2 + k2) * HWSZ + hw];

    float y  = (float)(ky + ho - PADV) + dy;
    float xc = (float)(kx + wo - PADV) + dx;
    float y0f = floorf(y), x0f = floorf(xc);
    float fy = y - y0f, fx = xc - x0f;
    int y0 = (int)y0f, x0 = (int)x0f;

    int   yy[2] = { y0, y0 + 1 };
    int   xx[2] = { x0, x0 + 1 };
    float wy[2] = { 1.f - fy, fy };
    float wx[2] = { 1.f - fx, fx };

    int base = t * 4;
    #pragma unroll
    for (int i = 0; i < 2; i++)
        #pragma unroll
        for (int j = 0; j < 2; j++) {
            int yi = yy[i], xi = xx[j];
            bool valid = (yi >= 0) && (yi < HH) && (xi >= 0) && (xi < WWID);
            int yc  = min(max(yi, 0), HH - 1);
            int xcc = min(max(xi, 0), WWID - 1);
            sidx[base + i * 2 + j] = yc * WWID + xcc;
            swgt[base + i * 2 + j] = valid ? (wy[i] * wx[j] * m) : 0.f;
        }
}

// ---------------------------------------------------------------------------
// sampling: build val bf16 [n][k], k = k2*256+cin, swizzled per row by n&7.
// Block = 16 pixels. thread: c8 = t&31 (8 cins), ps = t>>5.
// ---------------------------------------------------------------------------
__global__ __launch_bounds__(256)
void k_sample(const float* __restrict__ xh, const int* __restrict__ sidx,
              const float* __restrict__ swgt, unsigned short* __restrict__ val) {
    __shared__ int   cidx[16 * K2 * 4];
    __shared__ float cwgt[16 * K2 * 4];
    int n0 = blockIdx.x * 16;
    int b  = n0 >> 12;
    int t  = threadIdx.x;
    int cbase = n0 * K2 * 4;
    for (int i = t; i < 16 * K2 * 4; i += 256) {
        cidx[i] = sidx[cbase + i];
        cwgt[i] = swgt[cbase + i];
    }
    __syncthreads();
    int c8 = t & 31, ps = t >> 5;
    const float* xb = xh + (size_t)b * HWSZ * CIN;
    #pragma unroll
    for (int i = 0; i < 2; i++) {
        int p = ps + 8 * i;
        int n = n0 + p;
        int skey = n & 7;
        for (int k2 = 0; k2 < K2; k2++) {
            int cb = (p * K2 + k2) * 4;
            float a0=0,a1=0,a2=0,a3=0,a4=0,a5=0,a6=0,a7=0;
            #pragma unroll
            for (int cor = 0; cor < 4; cor++) {
                float wv = cwgt[cb + cor];
                const float4* px = (const float4*)(xb + (size_t)cidx[cb + cor] * CIN + c8 * 8);
                float4 lo = px[0], hi = px[1];
                a0 += wv * lo.x; a1 += wv * lo.y; a2 += wv * lo.z; a3 += wv * lo.w;
                a4 += wv * hi.x; a5 += wv * hi.y; a6 += wv * hi.z; a7 += wv * hi.w;
            }
            union { unsigned short s[8]; uint4 q; } pk;
            pk.s[0]=f2bf(a0); pk.s[1]=f2bf(a1); pk.s[2]=f2bf(a2); pk.s[3]=f2bf(a3);
            pk.s[4]=f2bf(a4); pk.s[5]=f2bf(a5); pk.s[6]=f2bf(a6); pk.s[7]=f2bf(a7);
            int phys = k2 * 512 + (c8 >> 3) * 128 + ((c8 & 7) ^ skey) * 16;
            *(uint4*)((char*)val + (size_t)n * ROWB + phys) = pk.q;
        }
    }
}

// ---------------------------------------------------------------------------
// GEMM: C[cout][n] = wtb[cout][k] * val[n][k]^T, 128x128x64 tiles, MFMA
// bf16 16x16x32. Epilogue: +bias, store, fused GroupNorm partial stats.
// ---------------------------------------------------------------------------
__global__ __launch_bounds__(256)
void k_gemm(const unsigned short* __restrict__ wtb, const unsigned short* __restrict__ val,
            const float* __restrict__ bias, float* __restrict__ out,
            float* __restrict__ gstat) {
    __shared__ unsigned short As[128 * 64];   // [m][k] swizzled, 16KB
    __shared__ unsigned short Bs[128 * 64];   // [n][k] swizzled, 16KB
    __shared__ float gs[16], gss[16];

    int mt = blockIdx.x, nt = blockIdx.y;
    int m0 = mt * 128, n0 = nt * 128;
    int t = threadIdx.x, w = t >> 6, l = t & 63;
    int r16 = l & 15, half = l >> 4;
    int wm = w & 1, wn = w >> 1;

    if (t < 16) { gs[t] = 0.f; gss[t] = 0.f; }

    // staging addresses: 1024 16B chunks per tile; chunk o -> row o>>3, u=o&7
    const char* ag[4]; const char* bg[4];
    unsigned short* lA[4]; unsigned short* lB[4];
    #pragma unroll
    for (int i = 0; i < 4; i++) {
        int o = (w * 4 + i) * 64 + l;
        int r = o >> 3, u = o & 7;
        ag[i] = (const char*)wtb + (size_t)(m0 + r) * ROWB + u * 16;
        bg[i] = (const char*)val + (size_t)(n0 + r) * ROWB + u * 16;
        lA[i] = (unsigned short*)As + (w * 4 + i) * 512;
        lB[i] = (unsigned short*)Bs + (w * 4 + i) * 512;
    }

    f32x4 acc[4][4];
    #pragma unroll
    for (int mi = 0; mi < 4; mi++)
        #pragma unroll
        for (int ni = 0; ni < 4; ni++) acc[mi][ni] = (f32x4)0.f;

    int skey = r16 & 7;
    for (int kc = 0; kc < NCHUNK; kc++) {
        #pragma unroll
        for (int i = 0; i < 4; i++) {
            GLOAD_LDS16(ag[i], lA[i]);
            GLOAD_LDS16(bg[i], lB[i]);
            ag[i] += 128; bg[i] += 128;
        }
        __syncthreads();   // drains vmcnt -> LDS tiles complete
        #pragma unroll
        for (int ks = 0; ks < 2; ks++) {
            int u = ((ks * 4 + half) ^ skey) * 8;
            bf16x8 af[4], bfv[4];
            #pragma unroll
            for (int mi = 0; mi < 4; mi++)
                af[mi] = *(const bf16x8*)&As[(wm * 64 + mi * 16 + r16) * 64 + u];
            #pragma unroll
            for (int ni = 0; ni < 4; ni++)
                bfv[ni] = *(const bf16x8*)&Bs[(wn * 64 + ni * 16 + r16) * 64 + u];
            #pragma unroll
            for (int mi = 0; mi < 4; mi++)
                #pragma unroll
                for (int ni = 0; ni < 4; ni++)
                    acc[mi][ni] = __builtin_amdgcn_mfma_f32_16x16x32_bf16(
                        af[mi], bfv[ni], acc[mi][ni], 0, 0, 0);
        }
        __syncthreads();
    }

    // epilogue: C/D mapping col=lane&15, row=(lane>>4)*4+reg
    int b = n0 >> 12;
    float s4[4] = {0,0,0,0}, ss4[4] = {0,0,0,0};
    #pragma unroll
    for (int mi = 0; mi < 4; mi++) {
        #pragma unroll
        for (int r = 0; r < 4; r++) {
            int co = m0 + wm * 64 + mi * 16 + half * 4 + r;
            float bs = bias[co];
            float* orow = out + ((size_t)(b * COUT + co)) * HWSZ;
            #pragma unroll
            for (int ni = 0; ni < 4; ni++) {
                int n = n0 + wn * 64 + ni * 16 + r16;
                float v = acc[mi][ni][r] + bs;
                orow[n & 4095] = v;
                s4[mi] += v; ss4[mi] += v * v;
            }
        }
    }
    int gb = half >> 1;
    #pragma unroll
    for (int mi = 0; mi < 4; mi++) {
        atomicAdd(&gs [wm * 8 + mi * 2 + gb], s4[mi]);
        atomicAdd(&gss[wm * 8 + mi * 2 + gb], ss4[mi]);
    }
    __syncthreads();
    if (t < 16) {
        int g = mt * 16 + t;
        atomicAdd(&gstat[((b * GROUPS) + g) * 2 + 0], gs[t]);
        atomicAdd(&gstat[((b * GROUPS) + g) * 2 + 1], gss[t]);
    }
}

// ---------------------------------------------------------------------------
// finalize: normalize + affine + ReLU in place (float4)
// ---------------------------------------------------------------------------
__global__ __launch_bounds__(256)
void k_gnfinal(float* __restrict__ out, const float* __restrict__ gstat,
               const float* __restrict__ gamma, const float* __restrict__ beta) {
    int i4 = blockIdx.x * 256 + threadIdx.x;
    int e  = i4 * 4;
    int c  = (e >> 12) & 255;
    int b  = e >> 20;
    int g  = c >> 3;
    float s  = gstat[((b * GROUPS) + g) * 2 + 0];
    float ss = gstat[((b * GROUPS) + g) * 2 + 1];
    const float inv = 1.f / (float)(CPG * HWSZ);
    float mu  = s * inv;
    float var = ss * inv - mu * mu;
    float rstd = rsqrtf(var + EPSV);
    float ga = gamma[c] * rstd;
    float be = beta[c] - mu * ga;
    float4 v = ((float4*)out)[i4];
    v.x = fmaxf(v.x * ga + be, 0.f);
    v.y = fmaxf(v.y * ga + be, 0.f);
    v.z = fmaxf(v.z * ga + be, 0.f);
    v.w = fmaxf(v.w * ga + be, 0.f);
    ((float4*)out)[i4] = v;
}

// ---------------------------------------------------------------------------
extern "C" void kernel_launch(void* const* d_in, const int* in_sizes, int n_in,
                              void* d_out, int out_size, void* d_ws, size_t ws_size,
                              hipStream_t stream) {
    const float* x      = (const float*)d_in[0];
    const float* offset = (const float*)d_in[1];
    const float* mask   = (const float*)d_in[2];
    const float* weight = (const float*)d_in[3];
    const float* bias   = (const float*)d_in[4];
    const float* gamma  = (const float*)d_in[5];
    const float* beta   = (const float*)d_in[6];
    float* out = (float*)d_out;

    // workspace layout (~98.2 MB)
    float*          xh    = (float*)d_ws;                       // 4,194,304 f
    unsigned short* wtb   = (unsigned short*)(xh + 4194304);    //   589,824 us
    int*            sidx  = (int*)(wtb + 589824);               // 2,359,296 B
    float*          swgt  = (float*)(sidx + 589824);            // 2,359,296 B
    unsigned short* val   = (unsigned short*)(swgt + 589824);   // 75,497,472 B
    float*          gstat = (float*)(val + (size_t)37748736);   // 256*2 f

    hipMemsetAsync(gstat, 0, GROUPS * BB * 2 * sizeof(float), stream);
    k_transpose_x<<<dim3(HWSZ / 32, CIN / 32, BB), dim3(32, 8), 0, stream>>>(x, xh);
    k_prep_w<<<(COUT * K2 * 32 + 255) / 256, 256, 0, stream>>>(weight, wtb);
    k_prep<<<(BB * HWSZ * K2 + 255) / 256, 256, 0, stream>>>(offset, mask, sidx, swgt);
    k_sample<<<NTOT / 16, 256, 0, stream>>>(xh, sidx, swgt, val);
    k_gemm<<<dim3(2, 128), 256, 0, stream>>>(wtb, val, bias, out, gstat);
    k_gnfinal<<<(size_t)BB * COUT * HWSZ / 1024, 256, 0, stream>>>(out, gstat, gamma, beta);
}

// Round 3
// 151.425 us; speedup vs baseline: 3.0931x; 1.1264x over previous
//
#include <hip/hip_runtime.h>
#include <math.h>

// Problem constants
#define BB    4
#define CIN   256
#define HH    64
#define WWID  64
#define COUT  256
#define KKS   3
#define K2    9
#define PADV  1
#define HWSZ  4096
#define GROUPS 32
#define CPG   8
#define EPSV  1e-5f
#define KTOT  2304          // K2*CIN
#define ROWB  4608          // KTOT * sizeof(bf16)
#define NTOT  16384         // BB*HWSZ
#define NCHUNK 18           // KTOT/128

typedef __attribute__((ext_vector_type(8))) short bf16x8;
typedef __attribute__((ext_vector_type(4))) float f32x4;

#define GLOAD_LDS16(g, l) \
    __builtin_amdgcn_global_load_lds((const __attribute__((address_space(1))) unsigned int*)(g), \
                                     (__attribute__((address_space(3))) unsigned int*)(l), 16, 0, 0)

__device__ __forceinline__ unsigned short f2bf(float f) {
    unsigned u = __float_as_uint(f);
    u = (u + 0x7fffu + ((u >> 16) & 1u)) >> 16;   // RNE
    return (unsigned short)u;
}
__device__ __forceinline__ float bflo(unsigned q) { return __uint_as_float(q << 16); }
__device__ __forceinline__ float bfhi(unsigned q) { return __uint_as_float(q & 0xffff0000u); }

// ---------------------------------------------------------------------------
// k_pre: grid (129, 8, 4).
//  bx<128 : x NCHW -> NHWC bf16 tile transpose
//  bx==128: weight [Cout][Cin][K2] -> bf16 [cout][k2*256+cin] swizzled
//           (+ block (128,0,0) zeroes gstat)
// ---------------------------------------------------------------------------
__global__ __launch_bounds__(256)
void k_pre(const float* __restrict__ x, unsigned short* __restrict__ xh,
           const float* __restrict__ w, unsigned short* __restrict__ wtb,
           float* __restrict__ gstat) {
    int t = threadIdx.x;
    if (blockIdx.x < 128) {
        __shared__ float tile[32][33];
        int hw0 = blockIdx.x * 32;
        int c0  = blockIdx.y * 32;
        int b   = blockIdx.z;
        int tx = t & 31, ty = t >> 5;
        const float* xp = x + (size_t)b * CIN * HWSZ;
        #pragma unroll
        for (int i = 0; i < 4; i++)
            tile[ty + i * 8][tx] = xp[(c0 + ty + i * 8) * HWSZ + hw0 + tx];
        __syncthreads();
        int j = t >> 3, cq = t & 7;      // row hw0+j, 4 channels cq*4..
        union { unsigned short s[4]; uint2 d; } pk;
        #pragma unroll
        for (int k = 0; k < 4; k++) pk.s[k] = f2bf(tile[cq * 4 + k][j]);
        *(uint2*)((char*)xh + ((size_t)b * HWSZ * CIN + (size_t)(hw0 + j) * CIN + c0 + cq * 4) * 2) = pk.d;
    } else {
        if (blockIdx.y == 0 && blockIdx.z == 0 && t < BB * GROUPS * 2) gstat[t] = 0.f;
        int idx = (blockIdx.y * 4 + blockIdx.z) * 256 + t;   // [0,8192)
        int co = idx >> 5, c8 = idx & 31;
        int cin0 = c8 * 8;
        for (int k2 = 0; k2 < K2; k2++) {
            union { unsigned short s[8]; uint4 q; } pk;
            #pragma unroll
            for (int j = 0; j < 8; j++)
                pk.s[j] = f2bf(w[(co * CIN + cin0 + j) * K2 + k2]);
            int phys = co * ROWB + k2 * 512 + (c8 >> 3) * 128 + ((c8 & 7) ^ (co & 7)) * 16;
            *(uint4*)((char*)wtb + phys) = pk.q;
        }
    }
}

// ---------------------------------------------------------------------------
// k_sample: fused corner-prep + bilinear sampling + modulate -> val bf16
// val row n (k-major, swizzled per row by n&7). Block = 16 pixels.
// ---------------------------------------------------------------------------
__global__ __launch_bounds__(256)
void k_sample(const unsigned short* __restrict__ xh,
              const float* __restrict__ offset, const float* __restrict__ mask,
              unsigned short* __restrict__ val) {
    __shared__ int   cidx[16 * K2 * 4];
    __shared__ float cwgt[16 * K2 * 4];
    int n0 = blockIdx.x * 16;
    int b  = n0 >> 12;
    int t  = threadIdx.x;

    if (t < 16 * K2) {                       // one (pixel, k2) per thread
        int p  = t / K2, k2 = t - p * K2;
        int hw = (n0 & 4095) + p;
        int ho = hw >> 6, wo = hw & 63;
        int ky = k2 / KKS, kx = k2 - ky * KKS;
        float dy = offset[((b * (2 * K2) + k2 * 2 + 0) * HWSZ) + hw];
        float dx = offset[((b * (2 * K2) + k2 * 2 + 1) * HWSZ) + hw];
        float m  = mask[(b * K2 + k2) * HWSZ + hw];
        float y  = (float)(ky + ho - PADV) + dy;
        float xc = (float)(kx + wo - PADV) + dx;
        float y0f = floorf(y), x0f = floorf(xc);
        float fy = y - y0f, fx = xc - x0f;
        int y0 = (int)y0f, x0 = (int)x0f;
        int   yy[2] = { y0, y0 + 1 };
        int   xx[2] = { x0, x0 + 1 };
        float wy[2] = { 1.f - fy, fy };
        float wx[2] = { 1.f - fx, fx };
        int base = t * 4;
        #pragma unroll
        for (int i = 0; i < 2; i++)
            #pragma unroll
            for (int j = 0; j < 2; j++) {
                int yi = yy[i], xi = xx[j];
                bool valid = (yi >= 0) && (yi < HH) && (xi >= 0) && (xi < WWID);
                int yc  = min(max(yi, 0), HH - 1);
                int xcc = min(max(xi, 0), WWID - 1);
                cidx[base + i * 2 + j] = yc * WWID + xcc;
                cwgt[base + i * 2 + j] = valid ? (wy[i] * wx[j] * m) : 0.f;
            }
    }
    __syncthreads();

    int c8 = t & 31, ps = t >> 5;
    const char* xb = (const char*)xh + (size_t)b * HWSZ * CIN * 2;
    #pragma unroll
    for (int i = 0; i < 2; i++) {
        int p = ps + 8 * i;
        int n = n0 + p;
        int skey = n & 7;
        for (int k2 = 0; k2 < K2; k2++) {
            int cb = (p * K2 + k2) * 4;
            float a0=0,a1=0,a2=0,a3=0,a4=0,a5=0,a6=0,a7=0;
            #pragma unroll
            for (int cor = 0; cor < 4; cor++) {
                float wv = cwgt[cb + cor];
                uint4 q = *(const uint4*)(xb + (size_t)cidx[cb + cor] * 512 + c8 * 16);
                a0 += wv * bflo(q.x); a1 += wv * bfhi(q.x);
                a2 += wv * bflo(q.y); a3 += wv * bfhi(q.y);
                a4 += wv * bflo(q.z); a5 += wv * bfhi(q.z);
                a6 += wv * bflo(q.w); a7 += wv * bfhi(q.w);
            }
            union { unsigned short s[8]; uint4 q; } pk;
            pk.s[0]=f2bf(a0); pk.s[1]=f2bf(a1); pk.s[2]=f2bf(a2); pk.s[3]=f2bf(a3);
            pk.s[4]=f2bf(a4); pk.s[5]=f2bf(a5); pk.s[6]=f2bf(a6); pk.s[7]=f2bf(a7);
            int phys = k2 * 512 + (c8 >> 3) * 128 + ((c8 & 7) ^ skey) * 16;
            *(uint4*)((char*)val + (size_t)n * ROWB + phys) = pk.q;
        }
    }
}

// ---------------------------------------------------------------------------
// k_gemm: C[cout][n] = wtb[cout][k] . val[n][k], tiles 128m x 64n x 128k,
// MFMA bf16 16x16x32, grid (2, 256) = 512 blocks (2/CU). Fused bias + GN stats.
// ---------------------------------------------------------------------------
__global__ __launch_bounds__(256)
void k_gemm(const unsigned short* __restrict__ wtb, const unsigned short* __restrict__ val,
            const float* __restrict__ bias, float* __restrict__ out,
            float* __restrict__ gstat) {
    __shared__ unsigned short As[128 * 128];  // 32 KB, [m][k] swizzled
    __shared__ unsigned short Bs[64 * 128];   // 16 KB, [n][k] swizzled
    __shared__ float gs[16], gss[16];

    int m0 = blockIdx.x * 128, n0 = blockIdx.y * 64;
    int t = threadIdx.x, w = t >> 6, l = t & 63;
    int r16 = l & 15, half = l >> 4;
    int wm = w & 1, wn = w >> 1;
    int skey = r16 & 7;

    if (t < 16) { gs[t] = 0.f; gss[t] = 0.f; }

    // staging: A 2048 16B-chunks (8/thread), B 1024 (4/thread); chunk o: row o>>4, u=o&15
    const char* ag[8]; unsigned short* lA[8];
    const char* bg[4]; unsigned short* lB[4];
    #pragma unroll
    for (int i = 0; i < 8; i++) {
        int o = (w * 8 + i) * 64 + l;
        ag[i] = (const char*)wtb + (size_t)(m0 + (o >> 4)) * ROWB + (o & 15) * 16;
        lA[i] = (unsigned short*)As + (w * 8 + i) * 512;
    }
    #pragma unroll
    for (int i = 0; i < 4; i++) {
        int o = (w * 4 + i) * 64 + l;
        bg[i] = (const char*)val + (size_t)(n0 + (o >> 4)) * ROWB + (o & 15) * 16;
        lB[i] = (unsigned short*)Bs + (w * 4 + i) * 512;
    }

    f32x4 acc[4][2];
    #pragma unroll
    for (int mi = 0; mi < 4; mi++)
        #pragma unroll
        for (int ni = 0; ni < 2; ni++) acc[mi][ni] = (f32x4)0.f;

    for (int kc = 0; kc < NCHUNK; kc++) {
        #pragma unroll
        for (int i = 0; i < 8; i++) { GLOAD_LDS16(ag[i], lA[i]); ag[i] += 256; }
        #pragma unroll
        for (int i = 0; i < 4; i++) { GLOAD_LDS16(bg[i], lB[i]); bg[i] += 256; }
        __syncthreads();
        #pragma unroll
        for (int ks = 0; ks < 4; ks++) {
            int ks4 = ks * 4 + half;
            int up  = ((ks4 & 8) | ((ks4 & 7) ^ skey)) * 8;   // shorts within row
            bf16x8 af[4], bfv[2];
            #pragma unroll
            for (int mi = 0; mi < 4; mi++)
                af[mi] = *(const bf16x8*)&As[(wm * 64 + mi * 16 + r16) * 128 + up];
            #pragma unroll
            for (int ni = 0; ni < 2; ni++)
                bfv[ni] = *(const bf16x8*)&Bs[(wn * 32 + ni * 16 + r16) * 128 + up];
            #pragma unroll
            for (int mi = 0; mi < 4; mi++)
                #pragma unroll
                for (int ni = 0; ni < 2; ni++)
                    acc[mi][ni] = __builtin_amdgcn_mfma_f32_16x16x32_bf16(
                        af[mi], bfv[ni], acc[mi][ni], 0, 0, 0);
        }
        __syncthreads();
    }

    // epilogue: C/D map col=lane&15 (n), row=half*4+reg (m)
    int b = n0 >> 12;
    float s4[4] = {0,0,0,0}, ss4[4] = {0,0,0,0};
    #pragma unroll
    for (int mi = 0; mi < 4; mi++) {
        #pragma unroll
        for (int r = 0; r < 4; r++) {
            int co = m0 + wm * 64 + mi * 16 + half * 4 + r;
            float bs = bias[co];
            float* orow = out + ((size_t)(b * COUT + co)) * HWSZ;
            #pragma unroll
            for (int ni = 0; ni < 2; ni++) {
                int n = (n0 + wn * 32 + ni * 16 + r16) & 4095;
                float v = acc[mi][ni][r] + bs;
                orow[n] = v;
                s4[mi] += v; ss4[mi] += v * v;
            }
        }
    }
    int gb = half >> 1;
    #pragma unroll
    for (int mi = 0; mi < 4; mi++) {
        atomicAdd(&gs [wm * 8 + mi * 2 + gb], s4[mi]);
        atomicAdd(&gss[wm * 8 + mi * 2 + gb], ss4[mi]);
    }
    __syncthreads();
    if (t < 16) {
        int g = blockIdx.x * 16 + t;
        atomicAdd(&gstat[((b * GROUPS) + g) * 2 + 0], gs[t]);
        atomicAdd(&gstat[((b * GROUPS) + g) * 2 + 1], gss[t]);
    }
}

// ---------------------------------------------------------------------------
// finalize: normalize + affine + ReLU in place (float4)
// ---------------------------------------------------------------------------
__global__ __launch_bounds__(256)
void k_gnfinal(float* __restrict__ out, const float* __restrict__ gstat,
               const float* __restrict__ gamma, const float* __restrict__ beta) {
    int i4 = blockIdx.x * 256 + threadIdx.x;
    int e  = i4 * 4;
    int c  = (e >> 12) & 255;
    int b  = e >> 20;
    int g  = c >> 3;
    float s  = gstat[((b * GROUPS) + g) * 2 + 0];
    float ss = gstat[((b * GROUPS) + g) * 2 + 1];
    const float inv = 1.f / (float)(CPG * HWSZ);
    float mu  = s * inv;
    float var = ss * inv - mu * mu;
    float rstd = rsqrtf(var + EPSV);
    float ga = gamma[c] * rstd;
    float be = beta[c] - mu * ga;
    float4 v = ((float4*)out)[i4];
    v.x = fmaxf(v.x * ga + be, 0.f);
    v.y = fmaxf(v.y * ga + be, 0.f);
    v.z = fmaxf(v.z * ga + be, 0.f);
    v.w = fmaxf(v.w * ga + be, 0.f);
    ((float4*)out)[i4] = v;
}

// ---------------------------------------------------------------------------
extern "C" void kernel_launch(void* const* d_in, const int* in_sizes, int n_in,
                              void* d_out, int out_size, void* d_ws, size_t ws_size,
                              hipStream_t stream) {
    const float* x      = (const float*)d_in[0];
    const float* offset = (const float*)d_in[1];
    const float* mask   = (const float*)d_in[2];
    const float* weight = (const float*)d_in[3];
    const float* bias   = (const float*)d_in[4];
    const float* gamma  = (const float*)d_in[5];
    const float* beta   = (const float*)d_in[6];
    float* out = (float*)d_out;

    // workspace (~85 MB)
    unsigned short* xh    = (unsigned short*)d_ws;              //  4,194,304 us (8.4 MB)
    unsigned short* wtb   = xh + (size_t)4194304;               //    589,824 us
    unsigned short* val   = wtb + (size_t)589824;               // 37,748,736 us (75.5 MB)
    float*          gstat = (float*)(val + (size_t)37748736);   // 256 f

    k_pre<<<dim3(129, 8, 4), 256, 0, stream>>>(x, xh, weight, wtb, gstat);
    k_sample<<<NTOT / 16, 256, 0, stream>>>(xh, offset, mask, val);
    k_gemm<<<dim3(2, 256), 256, 0, stream>>>(wtb, val, bias, out, gstat);
    k_gnfinal<<<(size_t)BB * COUT * HWSZ / 1024, 256, 0, stream>>>(out, gstat, gamma, beta);
}